// Round 1
// baseline (73.348 us; speedup 1.0000x reference)
//
#include <hip/hip_runtime.h>
#include <hip/hip_bf16.h>

#define NS 2048          // speakers (= cols)
#define MU 16            // utterances
#define DD 256           // dim (= K)
#define NMROWS (NS*MU)   // 32768 rows
#define KCN 32           // K / 8 chunks
#define BM 64            // rows per block
#define BN 64            // cols per tile
#define NT (NS/BN)       // 32 col tiles

typedef float  f32x4  __attribute__((ext_vector_type(4)));
typedef float  f32x16 __attribute__((ext_vector_type(16)));
typedef short  bf16x8 __attribute__((ext_vector_type(8)));
typedef unsigned short ushort8 __attribute__((ext_vector_type(8)));

#define LOG2E 1.44269504088896340736f
#define LN2   0.69314718055994530942f

#if __has_builtin(__builtin_amdgcn_exp2f)
#define EXP2F(x) __builtin_amdgcn_exp2f(x)
#else
#define EXP2F(x) exp2f(x)
#endif
#if __has_builtin(__builtin_amdgcn_logf)
#define LOG2F(x) __builtin_amdgcn_logf(x)   // v_log_f32 = log2
#else
#define LOG2F(x) __log2f(x)
#endif

__device__ __forceinline__ unsigned short f2bf(float x){
  unsigned u = __builtin_bit_cast(unsigned, x);
  u += 0x7fffu + ((u >> 16) & 1u);          // RNE
  return (unsigned short)(u >> 16);
}

// ---- prep: per-(n,d) sum over M; centroids scaled by w*log2e, bf16, k-major ----
__global__ void prep_kernel(const float* __restrict__ emb,
                            const float* __restrict__ wp,
                            float* __restrict__ sums,
                            unsigned short* __restrict__ centk){
  int idx = blockIdx.x*256 + threadIdx.x;   // n*256 + d
  int n = idx >> 8, d = idx & 255;
  const float* p = emb + (size_t)n*MU*DD + d;
  float s = 0.f;
  #pragma unroll
  for (int m=0;m<MU;m++) s += p[(size_t)m*DD];
  sums[idx] = s;
  float w2 = wp[0] * LOG2E;
  float c = s * (w2 * (1.0f/16.0f));        // w2 * centroid
  // centk[kc][col=n][j]  (kc = d>>3, j = d&7)
  centk[((size_t)(d>>3)*NS + n)*8 + (d&7)] = f2bf(c);
}

// ---- diag2[i] = w*log2e * dot(e_i, sums[spk]-e_i) / 15  (exact fp32) ----
__global__ void diag_kernel(const float* __restrict__ emb,
                            const float* __restrict__ sums,
                            const float* __restrict__ wp,
                            float* __restrict__ diag2){
  int row  = blockIdx.x*4 + (threadIdx.x>>6);
  int lane = threadIdx.x & 63;
  const float* e = emb  + (size_t)row*DD;
  const float* s = sums + (size_t)(row>>4)*DD;
  float acc = 0.f;
  #pragma unroll
  for (int i=0;i<4;i++){
    int k = lane + i*64;
    float ev = e[k];
    acc += ev * (s[k] - ev);
  }
  #pragma unroll
  for (int off=32; off; off>>=1) acc += __shfl_xor(acc, off, 64);
  if (lane==0) diag2[row] = acc * (wp[0] * LOG2E * (1.0f/15.0f));
}

// ---- main fused GEMM + online log2-softmax ----
__launch_bounds__(256)
__global__ void ge2e_main(const float* __restrict__ emb,
                          const unsigned short* __restrict__ centk,
                          const float* __restrict__ diag2,
                          float* __restrict__ partials){
  __shared__ unsigned short A_lds[KCN][BM][8];   // 32 KiB  (emb rows, bf16, k-major)
  __shared__ unsigned short B_lds[KCN][BN][8];   // 32 KiB  (scaled centroids)
  __shared__ float red_m[2][BM];
  __shared__ float red_s[2][BM];

  const int tid  = threadIdx.x;
  const int lane = tid & 63;
  const int wave = tid >> 6;
  const int wr = wave >> 1, wc = wave & 1;
  const int l31 = lane & 31, hi = lane >> 5;
  const int row0 = blockIdx.x * BM;

  // stage A: 64 rows x 256 k, f32 -> bf16, LDS layout [kc][row][8]
  {
    const float* src = emb + (size_t)row0 * DD;
    #pragma unroll
    for (int c=0;c<8;c++){
      int gc = tid + c*256;          // 0..2047
      int r = gc >> 5, kc = gc & 31;
      const float* q = src + (size_t)r*DD + kc*8;
      f32x4 v0 = *(const f32x4*)q;
      f32x4 v1 = *(const f32x4*)(q+4);
      ushort8 o;
      o[0]=f2bf(v0[0]); o[1]=f2bf(v0[1]); o[2]=f2bf(v0[2]); o[3]=f2bf(v0[3]);
      o[4]=f2bf(v1[0]); o[5]=f2bf(v1[1]); o[6]=f2bf(v1[2]); o[7]=f2bf(v1[3]);
      *(ushort8*)&A_lds[kc][r][0] = o;
    }
  }

  const int   myrow  = row0 + wr*32 + l31;  // this lane's embedding row
  const float dv     = diag2[myrow];
  const int   label  = myrow >> 4;          // its speaker = its diag column
  const int   diagct = (int)(blockIdx.x >> 4); // the one tile holding this block's labels

  float m = -3.0e38f, s = 0.f;

  for (int ct=0; ct<NT; ++ct){
    __syncthreads();                        // prev tile's B reads done
    // stage B tile: [kc][col][8] from k-major global (contiguous 16B, conflict-free)
    #pragma unroll
    for (int c=0;c<8;c++){
      int gc = tid + c*256;                 // slot = kc*64 + col
      int kc = gc >> 6, col = gc & 63;
      ushort8 v = *(const ushort8*)(centk + ((size_t)kc*NS + (size_t)ct*BN + col)*8);
      *(ushort8*)&B_lds[kc][col][0] = v;
    }
    __syncthreads();

    f32x16 acc;
    #pragma unroll
    for (int i=0;i<16;i++) acc[i] = 0.f;

    // swapped operands: D[col_local][row] so each lane owns ONE row
    #pragma unroll
    for (int st=0; st<16; ++st){
      int kc = 2*st + hi;
      bf16x8 eb = *(const bf16x8*)&A_lds[kc][wr*32 + l31][0];
      bf16x8 cb = *(const bf16x8*)&B_lds[kc][wc*32 + l31][0];
      acc = __builtin_amdgcn_mfma_f32_32x32x16_bf16(cb, eb, acc, 0, 0, 0);
    }

    // diag replacement (one tile per block, block-uniform branch)
    if (ct == diagct){
      #pragma unroll
      for (int r=0;r<16;r++){
        int col = ct*BN + wc*32 + (r&3) + 8*(r>>2) + 4*hi;
        if (col == label) acc[r] = dv;
      }
    }

    // online softmax, log2 domain; lane-local (16 cols of my row)
    float tm = fmaxf(fmaxf(fmaxf(acc[0],acc[1]),fmaxf(acc[2],acc[3])),
                     fmaxf(fmaxf(acc[4],acc[5]),fmaxf(acc[6],acc[7])));
    tm = fmaxf(tm, fmaxf(fmaxf(fmaxf(acc[8],acc[9]),fmaxf(acc[10],acc[11])),
                         fmaxf(fmaxf(acc[12],acc[13]),fmaxf(acc[14],acc[15]))));
    float mn = fmaxf(m, tm);
    float sc = EXP2F(m - mn);
    float ss = 0.f;
    #pragma unroll
    for (int r=0;r<16;r++) ss += EXP2F(acc[r] - mn);
    s = s*sc + ss;
    m = mn;
  }

  // merge the two half-wave partials (same row, disjoint cols)
  float mo = __shfl_xor(m, 32, 64);
  float so = __shfl_xor(s, 32, 64);
  float mt = fmaxf(m, mo);
  float st = s*EXP2F(m-mt) + so*EXP2F(mo-mt);

  if (hi==0){ red_m[wc][wr*32+l31]=mt; red_s[wc][wr*32+l31]=st; }
  __syncthreads();

  // merge across the two col-waves, form per-row loss term, block-reduce
  if (tid < 64){
    float m0=red_m[0][tid], s0=red_s[0][tid];
    float m1=red_m[1][tid], s1=red_s[1][tid];
    float mm = fmaxf(m0,m1);
    float ssum = s0*EXP2F(m0-mm) + s1*EXP2F(m1-mm);
    float term = LN2*(mm + LOG2F(ssum) - diag2[row0+tid]);
    #pragma unroll
    for (int off=32; off; off>>=1) term += __shfl_xor(term, off, 64);
    if (tid==0) partials[blockIdx.x] = term;
  }
}

__global__ void final_kernel(const float* __restrict__ partials,
                             float* __restrict__ out){
  __shared__ float sh[4];
  int tid = threadIdx.x;          // 256
  float v = 0.f;
  for (int i=tid; i<NMROWS/BM; i+=256) v += partials[i];
  #pragma unroll
  for (int off=32; off; off>>=1) v += __shfl_xor(v, off, 64);
  if ((tid&63)==0) sh[tid>>6] = v;
  __syncthreads();
  if (tid==0) out[0] = (sh[0]+sh[1]+sh[2]+sh[3]) * (1.0f/NMROWS);
}

extern "C" void kernel_launch(void* const* d_in, const int* in_sizes, int n_in,
                              void* d_out, int out_size, void* d_ws, size_t ws_size,
                              hipStream_t stream){
  const float* emb = (const float*)d_in[0];
  const float* wp  = (const float*)d_in[1];
  // d_in[2] (b) cancels in the loss; unused.
  float* out = (float*)d_out;
  char* ws = (char*)d_ws;

  float*          sums   = (float*)ws;                                    // 2 MiB
  unsigned short* centk  = (unsigned short*)(ws + (size_t)NS*DD*4);       // 1 MiB
  float*          diag2  = (float*)(ws + (size_t)NS*DD*4 + (size_t)NS*DD*2); // 128 KiB
  float*          parts  = diag2 + NMROWS;                                // 2 KiB

  prep_kernel <<<(NS*DD)/256, 256, 0, stream>>>(emb, wp, sums, centk);
  diag_kernel <<<NMROWS/4,    256, 0, stream>>>(emb, sums, wp, diag2);
  ge2e_main   <<<NMROWS/BM,   256, 0, stream>>>(emb, centk, diag2, parts);
  final_kernel<<<1,           256, 0, stream>>>(parts, out);
}

// Round 2
// 64.248 us; speedup vs baseline: 1.1416x; 1.1416x over previous
//
#include <hip/hip_runtime.h>
#include <hip/hip_bf16.h>

#define NS 2048          // speakers (= cols)
#define MU 16            // utterances
#define DD 256           // dim (= K)
#define NMROWS (NS*MU)   // 32768 rows
#define KCN 32           // K / 8 chunks
#define BM 64            // rows per block
#define BN 64            // cols per tile
#define NT (NS/BN)       // 32 col tiles

typedef float  f32x4  __attribute__((ext_vector_type(4)));
typedef float  f32x16 __attribute__((ext_vector_type(16)));
typedef short  bf16x8 __attribute__((ext_vector_type(8)));
typedef unsigned short ushort8 __attribute__((ext_vector_type(8)));

#define LOG2E 1.44269504088896340736f
#define LN2   0.69314718055994530942f

#if __has_builtin(__builtin_amdgcn_exp2f)
#define EXP2F(x) __builtin_amdgcn_exp2f(x)
#else
#define EXP2F(x) exp2f(x)
#endif
#if __has_builtin(__builtin_amdgcn_logf)
#define LOG2F(x) __builtin_amdgcn_logf(x)   // v_log_f32 = log2
#else
#define LOG2F(x) __log2f(x)
#endif

__device__ __forceinline__ unsigned short f2bf(float x){
  unsigned u = __builtin_bit_cast(unsigned, x);
  u += 0x7fffu + ((u >> 16) & 1u);          // RNE
  return (unsigned short)(u >> 16);
}

// ---- fused prep: per-speaker sums (local), scaled bf16 centroids (k-major),
// ---- exact-fp32 excluded-self diagonal, emb read ONCE ----
__launch_bounds__(256)
__global__ void prep_kernel(const float* __restrict__ emb,
                            const float* __restrict__ wp,
                            unsigned short* __restrict__ centk,
                            float* __restrict__ diag2){
  __shared__ float E[16*260];    // 16 rows x 256 dims, pad stride 260 (16B-aligned)
  __shared__ float sm[256];
  const int t = threadIdx.x;
  const int n = blockIdx.x;      // speaker
  const float* src = emb + (size_t)n*MU*DD;

  #pragma unroll
  for (int i=0;i<4;i++){
    int g = i*1024 + t*4;                 // coalesced f32x4
    f32x4 v = *(const f32x4*)(src + g);
    int m = g >> 8, d = g & 255;
    *(f32x4*)&E[m*260 + d] = v;
  }
  __syncthreads();

  {
    float s = 0.f;
    #pragma unroll
    for (int m=0;m<16;m++) s += E[m*260 + t];
    sm[t] = s;
  }
  __syncthreads();

  const float w2 = wp[0] * LOG2E;

  if (t < 32){                            // scaled centroid, bf16, k-major
    const float c16 = w2 * (1.0f/16.0f);
    ushort8 o;
    #pragma unroll
    for (int j=0;j<8;j++) o[j] = f2bf(sm[t*8+j]*c16);
    *(ushort8*)(centk + ((size_t)t*NS + n)*8) = o;
  }

  {                                       // excluded-self diagonal (exact fp32)
    int m = t >> 4, j = t & 15;
    float acc = 0.f;
    #pragma unroll
    for (int i=0;i<16;i++){
      int d = j + 16*i;
      float e = E[m*260 + d];
      acc += e * (sm[d] - e);
    }
    acc += __shfl_xor(acc, 1, 16);
    acc += __shfl_xor(acc, 2, 16);
    acc += __shfl_xor(acc, 4, 16);
    acc += __shfl_xor(acc, 8, 16);
    if (j==0) diag2[n*16 + m] = acc * (w2 * (1.0f/15.0f));
  }
}

// ---- stage one 64-col B tile (32 KiB) via async global->LDS DMA ----
__device__ __forceinline__ void stage_b(const unsigned short* __restrict__ centk,
                                        unsigned short (*buf)[BN][8],
                                        int ct, int wave, int lane){
  const unsigned short* g = centk + ((size_t)(wave*8)*NS + (size_t)ct*BN)*8 + (size_t)lane*8;
  unsigned short* l = &buf[wave*8][0][0];
  #pragma unroll
  for (int i=0;i<8;i++){
    __builtin_amdgcn_global_load_lds(
        (const __attribute__((address_space(1))) void*)g,
        (__attribute__((address_space(3))) void*)l,
        16, 0, 0);
    g += (size_t)NS*8;   // next kc row in global
    l += BN*8;           // next kc row in LDS
  }
}

// ---- main fused GEMM + online log2-softmax (A in regs, B double-buffered) ----
__launch_bounds__(256)
__global__ void ge2e_main(const float* __restrict__ emb,
                          const unsigned short* __restrict__ centk,
                          const float* __restrict__ diag2,
                          float* __restrict__ partials){
  __shared__ unsigned short Bbuf[2][KCN][BN][8];   // 64 KiB double-buffered B
  __shared__ float red_m[2][BM];
  __shared__ float red_s[2][BM];

  const int tid  = threadIdx.x;
  const int lane = tid & 63;
  const int wave = tid >> 6;
  const int wr = wave >> 1, wc = wave & 1;
  const int l31 = lane & 31, hi = lane >> 5;
  const int row0 = blockIdx.x * BM;
  const int myrow = row0 + wr*32 + l31;

  // issue tile-0 B staging ASAP
  stage_b(centk, Bbuf[0], 0, wave, lane);

  // hoist A fragments (this lane's embedding row, bf16) into 64 VGPRs
  bf16x8 af[16];
  {
    const float* rp = emb + (size_t)myrow*DD;
    #pragma unroll
    for (int st=0; st<16; ++st){
      int kc = 2*st + hi;
      f32x4 v0 = *(const f32x4*)(rp + kc*8);
      f32x4 v1 = *(const f32x4*)(rp + kc*8 + 4);
      bf16x8 o;
      o[0]=(short)f2bf(v0[0]); o[1]=(short)f2bf(v0[1]);
      o[2]=(short)f2bf(v0[2]); o[3]=(short)f2bf(v0[3]);
      o[4]=(short)f2bf(v1[0]); o[5]=(short)f2bf(v1[1]);
      o[6]=(short)f2bf(v1[2]); o[7]=(short)f2bf(v1[3]);
      af[st] = o;
    }
  }

  const float dv     = diag2[myrow];
  const int   label  = myrow >> 4;
  const int   diagct = blockIdx.x >> 4;   // the one tile holding this block's labels

  __syncthreads();   // full drain once: tile-0 B staged, A loads landed

  float m = -3.0e38f, s = 0.f;

  for (int ct=0; ct<NT; ++ct){
    const int cur = ct & 1;
    if (ct+1 < NT) stage_b(centk, Bbuf[cur^1], ct+1, wave, lane);  // prefetch

    f32x16 acc;
    #pragma unroll
    for (int i=0;i<16;i++) acc[i] = 0.f;

    #pragma unroll
    for (int st=0; st<16; ++st){
      bf16x8 cb = *(const bf16x8*)&Bbuf[cur][2*st+hi][wc*32 + l31][0];
      acc = __builtin_amdgcn_mfma_f32_32x32x16_bf16(cb, af[st], acc, 0, 0, 0);
    }

    if (ct == diagct){                    // block-uniform branch, once
      #pragma unroll
      for (int r=0;r<16;r++){
        int col = ct*BN + wc*32 + (r&3) + 8*(r>>2) + 4*hi;
        if (col == label) acc[r] = dv;
      }
    }

    // online softmax (log2 domain), lane-local
    float t0 = fmaxf(fmaxf(acc[0],acc[1]),acc[2]);
    float t1 = fmaxf(fmaxf(acc[3],acc[4]),acc[5]);
    float t2 = fmaxf(fmaxf(acc[6],acc[7]),acc[8]);
    float t3 = fmaxf(fmaxf(acc[9],acc[10]),acc[11]);
    float t4 = fmaxf(fmaxf(acc[12],acc[13]),acc[14]);
    float tm = fmaxf(fmaxf(fmaxf(t0,t1),t2), fmaxf(fmaxf(t3,t4),acc[15]));
    float mn = fmaxf(m, tm);
    float e0 = EXP2F(acc[0]-mn)+EXP2F(acc[1]-mn)+EXP2F(acc[2]-mn)+EXP2F(acc[3]-mn);
    float e1 = EXP2F(acc[4]-mn)+EXP2F(acc[5]-mn)+EXP2F(acc[6]-mn)+EXP2F(acc[7]-mn);
    float e2 = EXP2F(acc[8]-mn)+EXP2F(acc[9]-mn)+EXP2F(acc[10]-mn)+EXP2F(acc[11]-mn);
    float e3 = EXP2F(acc[12]-mn)+EXP2F(acc[13]-mn)+EXP2F(acc[14]-mn)+EXP2F(acc[15]-mn);
    s = s*EXP2F(m-mn) + ((e0+e1)+(e2+e3));
    m = mn;

    asm volatile("s_waitcnt vmcnt(0)" ::: "memory");  // own prefetch landed
    __builtin_amdgcn_s_barrier();                     // buffers safe to swap
  }

  // merge the two half-wave partials (same row, disjoint cols)
  float mo = __shfl_xor(m, 32, 64);
  float so = __shfl_xor(s, 32, 64);
  float mt = fmaxf(m, mo);
  float st = s*EXP2F(m-mt) + so*EXP2F(mo-mt);

  if (hi==0){ red_m[wc][wr*32+l31]=mt; red_s[wc][wr*32+l31]=st; }
  __syncthreads();

  if (tid < 64){
    float m0=red_m[0][tid], s0=red_s[0][tid];
    float m1=red_m[1][tid], s1=red_s[1][tid];
    float mm = fmaxf(m0,m1);
    float ssum = s0*EXP2F(m0-mm) + s1*EXP2F(m1-mm);
    float term = LN2*(mm + LOG2F(ssum) - diag2[row0+tid]);
    #pragma unroll
    for (int off=32; off; off>>=1) term += __shfl_xor(term, off, 64);
    if (tid==0) partials[blockIdx.x] = term;
  }
}

__global__ void final_kernel(const float* __restrict__ partials,
                             float* __restrict__ out){
  __shared__ float sh[4];
  int tid = threadIdx.x;          // 256
  float v = 0.f;
  for (int i=tid; i<NMROWS/BM; i+=256) v += partials[i];
  #pragma unroll
  for (int off=32; off; off>>=1) v += __shfl_xor(v, off, 64);
  if ((tid&63)==0) sh[tid>>6] = v;
  __syncthreads();
  if (tid==0) out[0] = (sh[0]+sh[1]+sh[2]+sh[3]) * (1.0f/NMROWS);
}

extern "C" void kernel_launch(void* const* d_in, const int* in_sizes, int n_in,
                              void* d_out, int out_size, void* d_ws, size_t ws_size,
                              hipStream_t stream){
  const float* emb = (const float*)d_in[0];
  const float* wp  = (const float*)d_in[1];
  // d_in[2] (b) cancels in the loss; unused.
  float* out = (float*)d_out;
  char* ws = (char*)d_ws;

  unsigned short* centk = (unsigned short*)ws;                  // 1 MiB
  float*          diag2 = (float*)(ws + (size_t)NS*DD*2);       // 128 KiB
  float*          parts = diag2 + NMROWS;                       // 2 KiB

  prep_kernel <<<NS,        256, 0, stream>>>(emb, wp, centk, diag2);
  ge2e_main   <<<NMROWS/BM, 256, 0, stream>>>(emb, centk, diag2, parts);
  final_kernel<<<1,         256, 0, stream>>>(parts, out);
}